// Round 4
// baseline (18030.261 us; speedup 1.0000x reference)
//
#include <hip/hip_runtime.h>
#include <math.h>

#define B_ 40
#define L_ 1000
#define H_ 512
#define A_ 300
#define T_ 20
#define E_ 300
#define V_ 78864
#define START_ 2

#define NBLK 256
#define NTHR 512

// ---------------- workspace layout (float offsets) ----------------
#define OFF_COPYK 0ul
#define OFF_M1T   12000000ul
#define OFF_M2T   12262144ul
#define OFF_BQK1  12524288ul
#define OFF_BQK2  12524800ul
#define OFF_QK    12525312ul
#define OFF_DEC   12545792ul
#define OFF_ATT1  12566272ul
#define OFF_ATTT  12578272ul
#define OFF_CPART 12590272ul
#define OFF_CSTAT 12713152ul
#define OFF_SCC   12713664ul
#define OFF_STT   12753664ul   /* zero region starts here */
#define OFF_ATT2  13081344ul
#define OFF_SELP  13093344ul
#define OFF_CNT   13216224ul
#define WS_END    13216288ul

struct P {
  const int* enc_in; const float* enc; const unsigned char* mask; const int* inputs;
  const float* embed;
  const float *e1Wih,*e1Whh,*e1b,*e2Wih,*e2Whh,*e2b;
  const float *inW,*inb;
  const float *r1Wih,*r1Whh,*r1b;
  const float *a1Wq,*a1bq,*a1Wk,*a1Wv,*a1bv;
  const float *r2Wih,*r2Whh,*r2b;
  const float *a2Wq,*a2bq,*a2Wk,*a2Wv,*a2bv;
  const float *cW,*cb,*oW,*ob,*scale;
  float* dout;
  float *copyK,*M1T,*M2T,*bqk1,*bqk2,*qk,*dec,*att1,*attT,*cpart,*cstat,*scc,*stt,*att2,*selp;
  unsigned* cnt;
};

__device__ __forceinline__ float sigm(float x){ return 1.0f/(1.0f+expf(-x)); }

__device__ __forceinline__ float wredSum(float v){
#pragma unroll
  for(int o=32;o>0;o>>=1) v+=__shfl_xor(v,o);
  return v;
}
__device__ __forceinline__ float wredMax(float v){
#pragma unroll
  for(int o=32;o>0;o>>=1) v=fmaxf(v,__shfl_xor(v,o));
  return v;
}

// device-scope grid barrier: monotone counter, memset to 0 before launch
__device__ __forceinline__ void gbar(unsigned* cnt, unsigned target){
  __syncthreads();
  if(threadIdx.x==0){
    __hip_atomic_fetch_add(cnt,1u,__ATOMIC_RELEASE,__HIP_MEMORY_SCOPE_AGENT);
    while(__hip_atomic_load(cnt,__ATOMIC_RELAXED,__HIP_MEMORY_SCOPE_AGENT)<target){
      __builtin_amdgcn_s_sleep(1);
    }
    (void)__hip_atomic_load(cnt,__ATOMIC_ACQUIRE,__HIP_MEMORY_SCOPE_AGENT);
  }
  __syncthreads();
}

// batched-40 GEMV accumulate over one input segment.
// xs: LDS [40*257]; each wave owns one W row (uniform); lane<40 = batch index.
// kq/nq: K-split among waves sharing a row (nq=1 for none).
template<typename SRC>
static __device__ __forceinline__ void gv_accum(float* xs,int K,const float* Wrow,
    float& acc,int lane,int kq,int nq,SRC src){
  for(int k0=0;k0<K;k0+=256){
    int ch=min(256,K-k0);
    __syncthreads();
    for(int i=threadIdx.x;i<40*ch;i+=NTHR){
      int bb=i/ch, kk=i-bb*ch;
      xs[bb*257+kk]=src(bb,k0+kk);
    }
    __syncthreads();
    if(lane<40){
#pragma unroll 4
      for(int k=kq;k<ch;k+=nq) acc+=Wrow[k0+k]*xs[lane*257+k];
    }
  }
}

// one LSTM cell for all 40 b: block owns 2 units x 4 gates (8 waves)
static __device__ void lstm_ph(const P& p,float* SH,float* gld,int t,
    const float* Wih,int XD,const float* Whh,const float* bias,
    const float* xvec,bool gather,
    const float* hr,const float* cr,float* hw,float* cw){
  int tid=threadIdx.x,w=tid>>6,lane=tid&63;
  int gate=w&3,usub=w>>2;
  int row=gate*H_+(blockIdx.x*2+usub);
  int rowu=__builtin_amdgcn_readfirstlane(row);
  float acc=bias[rowu];
  const float* W1=Wih+(size_t)rowu*XD;
  if(gather){
    const int* inp=p.inputs; const float* emb=p.embed; int tt=t;
    gv_accum(SH,XD,W1,acc,lane,0,1,[=](int bb,int kk)->float{
      int si=(tt==0)?START_:inp[bb*T_+tt-1];
      return emb[(size_t)si*E_+kk];});
  }else{
    gv_accum(SH,XD,W1,acc,lane,0,1,[=](int bb,int kk)->float{
      return xvec[(size_t)bb*XD+kk];});
  }
  const float* W2=Whh+(size_t)rowu*H_;
  gv_accum(SH,H_,W2,acc,lane,0,1,[=](int bb,int kk)->float{
    return hr[bb*H_+kk];});
  gld[w*64+lane]=acc;
  __syncthreads();
  if(w<2&&lane<40){
    int u=blockIdx.x*2+w,b=lane;
    float gi=gld[(w*4+0)*64+b],gf=gld[(w*4+1)*64+b],gg=gld[(w*4+2)*64+b],go=gld[(w*4+3)*64+b];
    float c=cr[b*H_+u];
    float cn=sigm(gf)*c+sigm(gi)*tanhf(gg);
    hw[b*H_+u]=sigm(go)*tanhf(cn);
    cw[b*H_+u]=cn;
  }
  __syncthreads();
}

// qk[b][h'] = bqk[h'] + sum_h hsrc[b][h] * MT[h'][h]
static __device__ void qk_ph(const P& p,float* SH,const float* hsrc,
    const float* MT,const float* bqk){
  int tid=threadIdx.x;
  if(blockIdx.x>=240) return;
  int b=blockIdx.x/6, j=blockIdx.x%6;
  SH[tid]=hsrc[b*H_+tid];
  __syncthreads();
  int h0=j*86, hc=min(86,H_-h0);
  if(tid<hc){
    int hp=h0+tid;
    float a=bqk[hp];
    const float4* mr=(const float4*)(MT+(size_t)hp*H_);
#pragma unroll 8
    for(int i=0;i<H_/4;i++){
      float4 m4=mr[i];
      a+=SH[4*i]*m4.x+SH[4*i+1]*m4.y+SH[4*i+2]*m4.z+SH[4*i+3]*m4.w;
    }
    p.qk[b*H_+hp]=a;
  }
}

// fused scores + online-softmax-weighted ctx partial for chunk j
static __device__ void scctx_ph(const P& p,float* SH,float* red){
  int tid=threadIdx.x,w=tid>>6,lane=tid&63;
  if(blockIdx.x>=240) return;
  int b=blockIdx.x/6, j=blockIdx.x%6;
  int l0=j*167, lcnt=min(167,L_-l0);
  const float* qrow=p.qk+b*H_;
  float4 q0=*(const float4*)(qrow+lane*8);
  float4 q1=*(const float4*)(qrow+lane*8+4);
  float m=-3.0e38f,S=0.f;
  float4 a0=make_float4(0.f,0.f,0.f,0.f), a1=a0;
  for(int l=l0+w;l<l0+lcnt;l+=8){
    const float4* er=(const float4*)(p.enc+((size_t)(b*L_+l))*H_);
    float4 e0=er[lane*2], e1=er[lane*2+1];
    float pp=q0.x*e0.x+q0.y*e0.y+q0.z*e0.z+q0.w*e0.w
            +q1.x*e1.x+q1.y*e1.y+q1.z*e1.z+q1.w*e1.w;
    pp=wredSum(pp);
    if(p.mask[b*L_+l]) pp=-1e9f;
    float mn=fmaxf(m,pp);
    float sc=expf(m-mn), pe=expf(pp-mn);
    S=S*sc+pe;
    a0.x=a0.x*sc+pe*e0.x; a0.y=a0.y*sc+pe*e0.y; a0.z=a0.z*sc+pe*e0.z; a0.w=a0.w*sc+pe*e0.w;
    a1.x=a1.x*sc+pe*e1.x; a1.y=a1.y*sc+pe*e1.y; a1.z=a1.z*sc+pe*e1.z; a1.w=a1.w*sc+pe*e1.w;
    m=mn;
  }
  *(float4*)(SH+w*H_+lane*8)=a0;
  *(float4*)(SH+w*H_+lane*8+4)=a1;
  if(lane==0){red[w]=m; red[8+w]=S;}
  __syncthreads();
  float mb=red[0];
#pragma unroll
  for(int q=1;q<8;q++) mb=fmaxf(mb,red[q]);
  float Sb=0.f;
#pragma unroll
  for(int q=0;q<8;q++) Sb+=red[8+q]*expf(red[q]-mb);
  float pv=0.f;
#pragma unroll
  for(int q=0;q<8;q++) pv+=expf(red[q]-mb)*SH[q*H_+tid];
  p.cpart[(size_t)(b*6+j)*H_+tid]=pv;
  if(tid==0){p.cstat[(b*6+j)*2]=mb; p.cstat[(b*6+j)*2+1]=Sb;}
}

// combine 6 ctx partials, project through Wv (+bv) -> att
static __device__ void atto_ph(const P& p,float* SH,const float* Wv,const float* bv,bool ADD){
  int tid=threadIdx.x;
  if(blockIdx.x>=40) return;
  int b=blockIdx.x;
  float mb=-3.0e38f;
#pragma unroll
  for(int j=0;j<6;j++) mb=fmaxf(mb,p.cstat[(b*6+j)*2]);
  float Sb=0.f;
#pragma unroll
  for(int j=0;j<6;j++) Sb+=p.cstat[(b*6+j)*2+1]*expf(p.cstat[(b*6+j)*2]-mb);
  float inv=1.0f/Sb;
  float cx=0.f;
#pragma unroll
  for(int j=0;j<6;j++) cx+=expf(p.cstat[(b*6+j)*2]-mb)*p.cpart[(size_t)(b*6+j)*H_+tid];
  SH[tid]=cx*inv;
  __syncthreads();
  if(tid<A_){
    float a=bv[tid];
    const float4* wr=(const float4*)(Wv+(size_t)tid*H_);
#pragma unroll 8
    for(int i=0;i<H_/4;i++){
      float4 w4=wr[i];
      a+=SH[4*i]*w4.x+SH[4*i+1]*w4.y+SH[4*i+2]*w4.z+SH[4*i+3]*w4.w;
    }
    if(ADD){ a+=p.att1[b*A_+tid]; p.att2[b*A_+tid]=a; p.attT[tid*B_+b]=a; }
    else p.att1[b*A_+tid]=a;
  }
}

// copy scores: scc[b][l] = att2[b] . copyK[b,l,:], masked
static __device__ void copysc_ph(const P& p){
  int tid=threadIdx.x,w=tid>>6,lane=tid&63;
  if(blockIdx.x>=240) return;
  int b=blockIdx.x/6, j=blockIdx.x%6;
  int l0=j*167, lcnt=min(167,L_-l0);
  float4 r0=*(const float4*)(p.att2+b*A_+lane*4);
  float4 r1=make_float4(0.f,0.f,0.f,0.f);
  if(lane<11) r1=*(const float4*)(p.att2+b*A_+256+lane*4);
  for(int l=l0+w;l<l0+lcnt;l+=8){
    const float4* cr=(const float4*)(p.copyK+((size_t)(b*L_+l))*A_);
    float4 c0=cr[lane];
    float pp=r0.x*c0.x+r0.y*c0.y+r0.z*c0.z+r0.w*c0.w;
    if(lane<11){
      float4 c1=cr[64+lane];
      pp+=r1.x*c1.x+r1.y*c1.y+r1.z*c1.z+r1.w*c1.w;
    }
    pp=wredSum(pp);
    if(lane==0) p.scc[b*L_+l]=p.mask[b*L_+l]?-1e9f:pp;
  }
}

// vocab rows v0..v0+311: acc over 40 b; W tile in LDS, attT via uniform s_load
static __device__ void vocab_ph(const P& p,float* SH,int t){
  int tid=threadIdx.x;
  int v0=blockIdx.x*312;
  if(v0>=V_) return;
  int vcnt=min(312,V_-v0);
  float acc[40];
#pragma unroll
  for(int b=0;b<40;b++) acc[b]=0.f;
  for(int c=0;c<10;c++){
    int a0=c*32, aw=min(32,A_-a0);
    __syncthreads();
    for(int i=tid;i<vcnt*aw;i+=NTHR){
      int vr=i/aw, ac=i-vr*aw;
      SH[vr*33+ac]=p.oW[(size_t)(v0+vr)*A_+a0+ac];
    }
    __syncthreads();
    if(tid<vcnt){
      for(int ac=0;ac<aw;ac++){
        float wv=SH[tid*33+ac];
        const float* at=p.attT+(a0+ac)*B_;
#pragma unroll
        for(int bq=0;bq<10;bq++){
          float4 t4=*(const float4*)(at+bq*4);
          acc[bq*4+0]+=wv*t4.x; acc[bq*4+1]+=wv*t4.y;
          acc[bq*4+2]+=wv*t4.z; acc[bq*4+3]+=wv*t4.w;
        }
      }
    }
  }
  if(tid<vcnt){
    int v=v0+tid;
    float obv=p.ob[v];
#pragma unroll
    for(int b=0;b<40;b++) p.dout[((size_t)(b*T_+t))*V_+v]=acc[b]+obv;
  }
}

// softmax(scc) stats (redundant per chunk) + scatter adds + sel partial
static __device__ void scatsel_ph(const P& p,float* SH,float* red,int t){
  int tid=threadIdx.x,w=tid>>6,lane=tid&63;
  if(blockIdx.x>=240) return;
  int b=blockIdx.x/6, j=blockIdx.x%6;
  int l0=j*167, lcnt=min(167,L_-l0);
  for(int i=tid;i<L_;i+=NTHR) SH[i]=p.scc[b*L_+i];
  __syncthreads();
  float lm=-3.0e38f;
  for(int i=tid;i<L_;i+=NTHR) lm=fmaxf(lm,SH[i]);
  lm=wredMax(lm);
  if(lane==0) red[w]=lm;
  __syncthreads();
  float m=red[0];
#pragma unroll
  for(int q=1;q<8;q++) m=fmaxf(m,red[q]);
  __syncthreads();
  int so=p.inputs[b*T_+t];
  float ls=0.f,lq=0.f;
  for(int i=tid;i<L_;i+=NTHR){
    float exv=expf(SH[i]-m);
    ls+=exv;
    if(p.enc_in[b*L_+i]==so) lq+=exv;
  }
  ls=wredSum(ls); lq=wredSum(lq);
  if(lane==0){red[w]=ls; red[8+w]=lq;}
  __syncthreads();
  float S=0.f,Q=0.f;
#pragma unroll
  for(int q=0;q<8;q++){S+=red[q];Q+=red[8+q];}
  if(tid<lcnt){
    int l=l0+tid;
    float exv=expf(SH[l]-m);
    SH[1024+tid]=(p.enc_in[b*L_+l]==so)?exv:0.f;
    float sc2=p.scale[0]*p.scale[0];
    atomicAdd(p.dout+((size_t)(b*T_+t))*V_+p.enc_in[b*L_+l], exv*sc2/S);
  }
  __syncthreads();
  float inv=1.0f/(Q+1e-8f*S);
  float a=0.f;
  for(int li=0;li<lcnt;li++)
    a+=SH[1024+li]*p.enc[((size_t)(b*L_+l0+li))*H_+tid];
  p.selp[(size_t)(b*6+j)*H_+tid]=a*inv;
}

// per-b argmax over full vocab row (first max wins) -> syms
static __device__ void argmax_ph(const P& p,float* SH,int t){
  int tid=threadIdx.x;
  if(blockIdx.x>=40) return;
  int b=blockIdx.x;
  const float* row=p.dout+((size_t)(b*T_+t))*V_;
  float best=-3.0e38f; int bi=0;
  for(int i4=tid;i4<V_/4;i4+=NTHR){
    float4 x=((const float4*)row)[i4];
    int base=i4*4;
    if(x.x>best){best=x.x;bi=base;}
    if(x.y>best){best=x.y;bi=base+1;}
    if(x.z>best){best=x.z;bi=base+2;}
    if(x.w>best){best=x.w;bi=base+3;}
  }
  int* isa=(int*)(SH+512);
  SH[tid]=best; isa[tid]=bi;
  __syncthreads();
  for(int off=256;off>0;off>>=1){
    if(tid<off){
      float ov=SH[tid+off]; int oi=isa[tid+off];
      if(ov>SH[tid]||(ov==SH[tid]&&oi<isa[tid])){SH[tid]=ov; isa[tid]=oi;}
    }
    __syncthreads();
  }
  if(tid==0) p.dout[(size_t)B_*T_*V_+b*T_+t]=(float)isa[0];
}

__global__ __launch_bounds__(NTHR,2) void k_persist(P p){
  __shared__ float SH[10320];
  __shared__ float gld[512];
  __shared__ float red[16];
  int blk=blockIdx.x, tid=threadIdx.x;
  unsigned bt=0;
#define BARR() do{bt++; gbar(p.cnt,bt*(unsigned)NBLK);}while(0)

  // ===== PREP: M1T/M2T = Wq^T@Wk (transposed), bqk = bq@Wk =====
  {
    int mm=blk>>7, r0=(blk&127)*4;
    const float* Wq = mm? p.a2Wq : p.a1Wq;
    const float* Wk = mm? p.a2Wk : p.a1Wk;
    float* MT = mm? p.M2T : p.M1T;
    float s0=0.f,s1=0.f,s2=0.f,s3=0.f;
    for(int a=0;a<A_;a++){
      float wq=Wq[a*H_+tid];
      s0+=wq*Wk[a*H_+r0+0];
      s1+=wq*Wk[a*H_+r0+1];
      s2+=wq*Wk[a*H_+r0+2];
      s3+=wq*Wk[a*H_+r0+3];
    }
    MT[(size_t)(r0+0)*H_+tid]=s0;
    MT[(size_t)(r0+1)*H_+tid]=s1;
    MT[(size_t)(r0+2)*H_+tid]=s2;
    MT[(size_t)(r0+3)*H_+tid]=s3;
    if((blk&127)==0){
      const float* bq = mm? p.a2bq : p.a1bq;
      float ab=0.f;
      for(int a=0;a<A_;a++) ab+=bq[a]*Wk[a*H_+tid];
      (mm? p.bqk2 : p.bqk1)[tid]=ab;
    }
  }
  // ===== PREP: copyK = tanh(enc @ cW^T + cb) =====
  for(int item=blk;item<B_*63;item+=NBLK){
    int b=item/63, lt=item-b*63;
    int l0=lt*16, lcnt=min(16,L_-l0);
    float acc[16];
    float bv=(tid<A_)?p.cb[tid]:0.f;
#pragma unroll
    for(int l=0;l<16;l++) acc[l]=bv;
    for(int k0=0;k0<H_;k0+=32){
      __syncthreads();
      for(int i=tid;i<A_*32;i+=NTHR){
        int a=i>>5,kc=i&31;
        SH[a*33+kc]=p.cW[(size_t)a*H_+k0+kc];
      }
      __syncthreads();
      if(tid<A_){
#pragma unroll
        for(int l=0;l<16;l++){
          if(l<lcnt){
            const float* es=p.enc+((size_t)(b*L_+l0+l))*H_+k0;
            float al=acc[l];
#pragma unroll
            for(int kc=0;kc<32;kc++) al+=SH[tid*33+kc]*es[kc];
            acc[l]=al;
          }
        }
      }
    }
    if(tid<A_){
#pragma unroll
      for(int l=0;l<16;l++)
        if(l<lcnt) p.copyK[((size_t)(b*L_+l0+l))*A_+tid]=tanhf(acc[l]);
    }
  }
  BARR();

  // ===== decoder steps =====
  for(int t=0;t<T_;t++){
    int rp=t&1, wp=rp^1;
    float* stt=p.stt;
    auto SL=[&](int i,int par){ return stt+((size_t)(i*2+par))*(B_*H_); };
    float *eh1r=SL(0,rp),*eh1w=SL(0,wp),*ec1r=SL(1,rp),*ec1w=SL(1,wp);
    float *eh2r=SL(2,rp),*eh2w=SL(2,wp),*ec2r=SL(3,rp),*ec2w=SL(3,wp);
    float *h1r=SL(4,rp),*h1w=SL(4,wp),*c1r=SL(5,rp),*c1w=SL(5,wp);
    float *h2r=SL(6,rp),*h2w=SL(6,wp),*c2r=SL(7,rp),*c2w=SL(7,wp);

    lstm_ph(p,SH,gld,t,p.e1Wih,E_,p.e1Whh,p.e1b,nullptr,true ,eh1r,ec1r,eh1w,ec1w); BARR();
    lstm_ph(p,SH,gld,t,p.e2Wih,H_,p.e2Whh,p.e2b,eh1w  ,false,eh2r,ec2r,eh2w,ec2w); BARR();

    { // dec_in = concat(emb, eh2, att2_prev, sel_prev) @ in_W^T + in_b + pe
      int w=tid>>6,lane=tid&63;
      int usub=w>>2, kq=w&3;
      int unit=blk*2+usub;
      int rowu=__builtin_amdgcn_readfirstlane(unit);
      float acc=0.f;
      const float* Wr=p.inW+(size_t)rowu*1624;
      const int* inp=p.inputs; const float* emb=p.embed;
      const float* e2=eh2w; const float* a2c=p.att2; const float* sp=p.selp;
      int tt=t;
      gv_accum(SH,1624,Wr,acc,lane,kq,4,[=](int bb,int kk)->float{
        if(kk<E_){int si=(tt==0)?START_:inp[bb*T_+tt-1];return emb[(size_t)si*E_+kk];}
        else if(kk<E_+H_) return e2[bb*H_+kk-E_];
        else if(kk<E_+H_+A_) return a2c[bb*A_+kk-(E_+H_)];
        else{
          int hh=kk-(E_+H_+A_); float s=0.f;
#pragma unroll
          for(int jj=0;jj<6;jj++) s+=sp[(size_t)(bb*6+jj)*H_+hh];
          return s;
        }
      });
      gld[(usub*4+kq)*64+lane]=acc;
      __syncthreads();
      if(w<2&&lane<40){
        int u=blk*2+w;
        float s=gld[(w*4+0)*64+lane]+gld[(w*4+1)*64+lane]
               +gld[(w*4+2)*64+lane]+gld[(w*4+3)*64+lane];
        float ex=(float)(2*(u>>1))/512.0f;
        float ang=(float)t/powf(10000.0f,ex);
        s+=p.inb[u]+((u&1)?cosf(ang):sinf(ang));
        p.dec[lane*H_+u]=s;
      }
      __syncthreads();
    }
    BARR();

    lstm_ph(p,SH,gld,t,p.r1Wih,H_,p.r1Whh,p.r1b,p.dec ,false,h1r,c1r,h1w,c1w); BARR();
    qk_ph(p,SH,h1w,p.M1T,p.bqk1);                                              BARR();
    scctx_ph(p,SH,red);                                                        BARR();
    atto_ph(p,SH,p.a1Wv,p.a1bv,false);                                         BARR();
    lstm_ph(p,SH,gld,t,p.r2Wih,A_,p.r2Whh,p.r2b,p.att1,false,h2r,c2r,h2w,c2w); BARR();
    qk_ph(p,SH,h2w,p.M2T,p.bqk2);                                              BARR();
    scctx_ph(p,SH,red);                                                        BARR();
    atto_ph(p,SH,p.a2Wv,p.a2bv,true);                                          BARR();
    copysc_ph(p);                                                              BARR();
    vocab_ph(p,SH,t);                                                          BARR();
    scatsel_ph(p,SH,red,t);                                                    BARR();
    argmax_ph(p,SH,t);
    // no barrier needed: next step's elmo1 touches no buffers argmax uses
  }
#undef BARR
}

extern "C" void kernel_launch(void* const* d_in, const int* in_sizes, int n_in,
                              void* d_out, int out_size, void* d_ws, size_t ws_size,
                              hipStream_t stream){
  P p;
  p.enc_in=(const int*)d_in[0];
  p.enc   =(const float*)d_in[1];
  p.mask  =(const unsigned char*)d_in[2];
  p.inputs=(const int*)d_in[3];
  p.embed =(const float*)d_in[4];
  p.e1Wih=(const float*)d_in[5];  p.e1Whh=(const float*)d_in[6];  p.e1b=(const float*)d_in[7];
  p.e2Wih=(const float*)d_in[8];  p.e2Whh=(const float*)d_in[9];  p.e2b=(const float*)d_in[10];
  p.inW  =(const float*)d_in[11]; p.inb  =(const float*)d_in[12];
  p.r1Wih=(const float*)d_in[13]; p.r1Whh=(const float*)d_in[14]; p.r1b=(const float*)d_in[15];
  p.a1Wq =(const float*)d_in[16]; p.a1bq =(const float*)d_in[17];
  p.a1Wk =(const float*)d_in[18];
  p.a1Wv =(const float*)d_in[20]; p.a1bv =(const float*)d_in[21];
  p.r2Wih=(const float*)d_in[22]; p.r2Whh=(const float*)d_in[23]; p.r2b=(const float*)d_in[24];
  p.a2Wq =(const float*)d_in[25]; p.a2bq =(const float*)d_in[26];
  p.a2Wk =(const float*)d_in[27];
  p.a2Wv =(const float*)d_in[29]; p.a2bv =(const float*)d_in[30];
  p.cW   =(const float*)d_in[31]; p.cb   =(const float*)d_in[32];
  p.oW   =(const float*)d_in[33]; p.ob   =(const float*)d_in[34];
  p.scale=(const float*)d_in[35];
  p.dout=(float*)d_out;

  float* w=(float*)d_ws;
  p.copyK=w+OFF_COPYK;
  p.M1T  =w+OFF_M1T;   p.M2T =w+OFF_M2T;
  p.bqk1 =w+OFF_BQK1;  p.bqk2=w+OFF_BQK2;
  p.qk   =w+OFF_QK;    p.dec =w+OFF_DEC;
  p.att1 =w+OFF_ATT1;  p.attT=w+OFF_ATTT;
  p.cpart=w+OFF_CPART; p.cstat=w+OFF_CSTAT;
  p.scc  =w+OFF_SCC;   p.stt =w+OFF_STT;
  p.att2 =w+OFF_ATT2;  p.selp=w+OFF_SELP;
  p.cnt  =(unsigned*)(w+OFF_CNT);

  // zero: LSTM states (both parities), att2 carry, sel partials, barrier counter
  hipMemsetAsync(w+OFF_STT,0,(WS_END-OFF_STT)*sizeof(float),stream);
  k_persist<<<NBLK,NTHR,0,stream>>>(p);
}